// Round 12
// baseline (3249.866 us; speedup 1.0000x reference)
//
#include <hip/hip_runtime.h>
#include <math.h>
#include <stdint.h>

#define NTAGS 512
#define SEQL  512
#define BATCH 64
#define START_TAG 510
#define STOP_TAG  511
#define NEG_INF  -10000.0f

#define NBLK 1024               // launched blocks (election pool)
#define P    64                 // participants (on the winning XCD)
#define BT   512                // 8 waves; participant wave w owns row 8*role + w
#define ROWS 8

// ws layout (bytes)
#define WS_NUM_OFF   0                    // float numerator accumulator
#define WS_CNT_OFF   16                   // int cnt[8] per-XCD ticket counters
#define WS_WIN_OFF   48                   // int winner (0 = unset, else xcd+1)
#define WS_FAST_OFF  256                  // uint64 fast slots [2][NTAGS] (winner-XCD L2)
#define WS_LLC_OFF   (WS_FAST_OFF + 2 * NTAGS * 8)   // uint64 LLC mirror [2][NTAGS]
#define WS_BYTES     (WS_LLC_OFF + 2 * NTAGS * 8)

#define AGLD(p)   __hip_atomic_load((p), __ATOMIC_RELAXED, __HIP_MEMORY_SCOPE_AGENT)
#define AGST(p,v) __hip_atomic_store((p), (v), __ATOMIC_RELAXED, __HIP_MEMORY_SCOPE_AGENT)

// L1-bypass, L2-cached access: within one XCD the shared L2 is the coherence point.
__device__ __forceinline__ uint64_t sc0_load(const uint64_t* p) {
    uint64_t r;
    asm volatile("global_load_dwordx2 %0, %1, off sc0\n\ts_waitcnt vmcnt(0)"
                 : "=v"(r) : "v"(p) : "memory");
    return r;
}
__device__ __forceinline__ void sc0_store(uint64_t* p, uint64_t v) {
    asm volatile("global_store_dwordx2 %0, %1, off sc0" :: "v"(p), "v"(v) : "memory");
}

__global__ __launch_bounds__(BT, 8) void crf_fused(
    const float* __restrict__ inputs, const int* __restrict__ tags,
    const float* __restrict__ trans, void* __restrict__ ws,
    float* __restrict__ out)
{
    __shared__ float fv_lds[2][NTAGS];    // 4 KB ping-pong forward variable
    __shared__ int   s_tkt, s_win;

    const int tid  = threadIdx.x;
    const int lane = tid & 63;
    const int wave = tid >> 6;

    float*    numacc = (float*)((char*)ws + WS_NUM_OFF);
    int*      cnt    = (int*)  ((char*)ws + WS_CNT_OFF);
    int*      winner = (int*)  ((char*)ws + WS_WIN_OFF);
    uint64_t* fast   = (uint64_t*)((char*)ws + WS_FAST_OFF);
    uint64_t* llc    = (uint64_t*)((char*)ws + WS_LLC_OFF);

    // ---- election: first XCD to seat P blocks wins; its tickets 0..P-1 play ----
    unsigned xcd;
    asm volatile("s_getreg_b32 %0, hwreg(HW_REG_XCC_ID)" : "=s"(xcd));
    xcd &= 7;
    if (tid == 0) {
        const int tkt = atomicAdd(&cnt[xcd], 1);
        if (tkt == P - 1) atomicCAS(winner, 0, (int)xcd + 1);
        s_tkt = tkt;
    }
    __syncthreads();
    if (tid == 0) {
        int w;
        while ((w = AGLD(winner)) == 0) __builtin_amdgcn_s_sleep(8);
        s_win = w;
    }
    __syncthreads();
    const int role = s_tkt;
    if ((int)xcd != s_win - 1 || role >= P) return;   // non-participants exit
    const int myrow = role * ROWS + wave;

    // ---- my transition row in REGISTERS ----
    float treg[8];
    {
        const float* trow = trans + (size_t)myrow * NTAGS;
        #pragma unroll
        for (int q = 0; q < 8; ++q) treg[q] = trow[lane + 64 * q];   // coalesced
    }

    // ---- numerator: participant role == batch role, thread t == position t ----
    float ns;
    {
        const int*   tg  = tags + role * SEQL;
        const float* inb = inputs + (size_t)role * SEQL * NTAGS;
        if (tid > 0) {
            const int cur = tg[tid], prev = tg[tid - 1];
            ns = trans[cur * NTAGS + prev] + inb[(size_t)(tid - 1) * NTAGS + cur];
        } else {
            ns = trans[tg[0] * NTAGS + START_TAG] + trans[STOP_TAG * NTAGS + tg[SEQL - 1]];
        }
    }
    #pragma unroll
    for (int off = 32; off; off >>= 1) ns += __shfl_xor(ns, off);
    if (lane == 0) atomicAdd(numacc, ns);
    __builtin_amdgcn_s_waitcnt(0);   // RMW retired at coherence point before any publish

    // init fv0 in LDS ping buffer 0
    fv_lds[0][tid] = (tid == START_TAG) ? 0.0f : NEG_INF;
    __syncthreads();

    // sum-shift = previous step's row max (step-0 value known analytically)
    float mprev = (myrow == START_TAG) ? NEG_INF : 0.0f;

    for (int s = 0; s < SEQL; ++s) {
        const int pp = (s + 1) & 1;
        uint64_t* fbuf = fast + (size_t)pp * NTAGS;
        uint64_t* lbuf = llc  + (size_t)pp * NTAGS;
        const unsigned want = (unsigned)(s + 1);
        const float* fvc = fv_lds[s & 1];

        // early probe of my slot (fast path): overlaps compute + publish
        uint64_t p = sc0_load(&fbuf[tid]);

        // ---- my row: v = fv + T[row]; m = max(v); ss = sum exp(v - mprev) ----
        float v[8];
        #pragma unroll
        for (int q = 0; q < 8; ++q)                 // 2-way LDS alias only (free)
            v[q] = fvc[lane + 64 * q] + treg[q];

        float m = fmaxf(fmaxf(fmaxf(v[0], v[1]), fmaxf(v[2], v[3])),
                        fmaxf(fmaxf(v[4], v[5]), fmaxf(v[6], v[7])));
        float ss = ((__expf(v[0] - mprev) + __expf(v[1] - mprev))
                  + (__expf(v[2] - mprev) + __expf(v[3] - mprev)))
                 + ((__expf(v[4] - mprev) + __expf(v[5] - mprev))
                  + (__expf(v[6] - mprev) + __expf(v[7] - mprev)));

        // two INDEPENDENT butterflies, interleaved -> single 6-stage latency
        #pragma unroll
        for (int off = 32; off; off >>= 1) {
            const float ms  = __shfl_xor(m, off);
            const float sss = __shfl_xor(ss, off);
            m  = fmaxf(m, ms);
            ss += sss;
        }

        // dual publish: fast (winner-XCD L2) + LLC mirror (correctness fallback)
        {
            const float nv = __logf(ss) + mprev - m;
            const uint64_t pk = ((uint64_t)want << 32) | (uint64_t)__float_as_uint(nv);
            if (lane == 0) {
                sc0_store(&fbuf[myrow], pk);
                AGST(&lbuf[myrow], pk);
            }
        }
        mprev = m;

        // ---- poll MY slot: fast path (L2, ~200cyc/iter); LLC probe every 16 ----
        if ((unsigned)(p >> 32) != want) {
            int it = 0;
            for (;;) {
                p = sc0_load(&fbuf[tid]);
                if ((unsigned)(p >> 32) == want) break;
                if (((++it) & 15) == 0) {
                    const uint64_t p2 = AGLD(&lbuf[tid]);
                    if ((unsigned)(p2 >> 32) == want) { p = p2; break; }
                }
            }
        }
        fv_lds[pp][tid] = __uint_as_float((unsigned)(p & 0xFFFFFFFFu));

        // lgkmcnt-only barrier: depth-2 safety without draining in-flight vm ops
        asm volatile("s_waitcnt lgkmcnt(0)\n\ts_barrier" ::: "memory");
    }

    // ---- terminal by the wave owning row STOP (role 63, wave 7): treg == T[STOP] ----
    if (myrow == STOP_TAG) {
        const float* fvf = fv_lds[0];               // tag 512 lives in buffer 0
        float v[8];
        #pragma unroll
        for (int q = 0; q < 8; ++q)
            v[q] = fvf[lane + 64 * q] + treg[q];
        float m = fmaxf(fmaxf(fmaxf(v[0], v[1]), fmaxf(v[2], v[3])),
                        fmaxf(fmaxf(v[4], v[5]), fmaxf(v[6], v[7])));
        // safe unshifted sum: real terms bounded by e^~11
        float ss = ((__expf(v[0]) + __expf(v[1])) + (__expf(v[2]) + __expf(v[3])))
                 + ((__expf(v[4]) + __expf(v[5])) + (__expf(v[6]) + __expf(v[7])));
        #pragma unroll
        for (int off = 32; off; off >>= 1) {
            const float ms  = __shfl_xor(m, off);
            const float sss = __shfl_xor(ss, off);
            m  = fmaxf(m, ms);
            ss += sss;
        }
        if (lane == 0) {
            const float ld  = __logf(ss) - m;       // log_denominator
            // tag-512 from every row => all numerator RMWs (pre-publish, drained) retired
            const float num = AGLD(numacc);
            out[0] = num - (float)BATCH * ld;
        }
    }
}

extern "C" void kernel_launch(void* const* d_in, const int* in_sizes, int n_in,
                              void* d_out, int out_size, void* d_ws, size_t ws_size,
                              hipStream_t stream)
{
    const float* inputs = (const float*)d_in[0];   // (64, 512, 512) fp32
    const int*   tags   = (const int*)  d_in[1];   // (64, 512) int32
    const float* trans  = (const float*)d_in[2];   // (512, 512) fp32
    float* out = (float*)d_out;

    // zero election counters, numerator accumulator, and slot tags (tags 1..512)
    hipMemsetAsync(d_ws, 0, WS_BYTES, stream);

    crf_fused<<<NBLK, BT, 0, stream>>>(inputs, tags, trans, d_ws, out);
}